// Round 17
// baseline (603.247 us; speedup 1.0000x reference)
//
#include <hip/hip_runtime.h>
#include <math.h>

static constexpr int BATCH = 64;
static constexpr int SEQ   = 32;
static constexpr int TOK   = BATCH * SEQ;   // 2048
static constexpr int DIM   = 1024;
static constexpr int NH    = 16;
static constexpr int HDIM  = 64;
static constexpr int FFD   = 2048;
static constexpr int LAYERS= 4;
static constexpr int NHEAD_OUT = 26;
static constexpr int IDH   = 512;

typedef __bf16 bf16_t;
typedef __bf16 bf16x4 __attribute__((ext_vector_type(4)));
typedef __bf16 bf16x8 __attribute__((ext_vector_type(8)));
typedef float  f32x4  __attribute__((ext_vector_type(4)));
typedef float  f32x16 __attribute__((ext_vector_type(16)));
typedef unsigned short us4 __attribute__((ext_vector_type(4)));
typedef unsigned short us8 __attribute__((ext_vector_type(8)));

__device__ __forceinline__ unsigned short f2bfu(float f) {
    return __builtin_bit_cast(unsigned short, (bf16_t)f);
}

__device__ __forceinline__ void gload_lds16(const void* gp, void* lp) {
    __builtin_amdgcn_global_load_lds(
        (const __attribute__((address_space(1))) unsigned int*)gp,
        (__attribute__((address_space(3))) unsigned int*)lp,
        16, 0, 0);
}

// ---------------- fragment-tiled transpose: 4 chunks of ONE matrix ----------
// chunk (ns,kt) = 4KB: [kk(4)][lane(64)][16B]; lane l: n = ns*32+(l&31),
// k = kt*64 + kk*16 + (l>>5)*8 + j.
// If g != nullptr: store g[k]*W[k][n] (LN-gamma folded into the weight) and
// atomically accumulate c1[n] += sum g[k]W[k][n], c2[n] += sum b[k]W[k][n].
__device__ __forceinline__ void tx_chunks4(const float* __restrict__ src,
                                           bf16_t* __restrict__ dst,
                                           int K, int N, int base4,
                                           const float* __restrict__ g,
                                           const float* __restrict__ b,
                                           float* __restrict__ c1,
                                           float* __restrict__ c2) {
    int nkb = K >> 6;
    int kk = threadIdx.x >> 6;
    int l  = threadIdx.x & 63;
    int nl = l & 31, k8 = (l >> 5) * 8;
    int base = base4 * 4;
    #pragma unroll
    for (int q = 0; q < 4; ++q) {
        int chunk = base + q;
        int ns = chunk / nkb;
        int kt = chunk - ns * nkb;
        int n = ns * 32 + nl;
        int kb = kt * 64 + kk * 16 + k8;
        us8 o;
        if (g != nullptr) {
            float s1 = 0.f, s2 = 0.f;
            #pragma unroll
            for (int j = 0; j < 8; ++j) {
                float w = src[(long)(kb + j) * N + n];
                float gg = g[kb + j];
                float sw = gg * w;
                s1 += sw;
                s2 += b[kb + j] * w;
                o[j] = f2bfu(sw);
            }
            atomicAdd(&c1[n], s1);
            atomicAdd(&c2[n], s2);
        } else {
            #pragma unroll
            for (int j = 0; j < 8; ++j)
                o[j] = f2bfu(src[(long)(kb + j) * N + n]);
        }
        *(us8*)(dst + (long)chunk * 2048 + kk * 512 + l * 8) = o;
    }
}

// ---------------- upfront transpose (layer-0 weights only) ----------------
struct TxPack {
    const float* src[4];
    bf16_t*      dst[4];
    const float* g[4];
    const float* b[4];
    float*       c1[4];
    float*       c2[4];
    int K[4], N[4];
    int blk0[4];
};

__global__ __launch_bounds__(256) void txd(TxPack p) {
    int bid = blockIdx.x;
    int s = 0;
    #pragma unroll
    for (int i = 1; i < 4; ++i) if (bid >= p.blk0[i]) s = i;
    tx_chunks4(p.src[s], p.dst[s], p.K[s], p.N[s], bid - p.blk0[s],
               p.g[s], p.b[s], p.c1[s], p.c2[s]);
}

// ---------------- LN stats: wave per row -> (mu, R) per row
// DBL: double LN (non-affine eps 1e-6 then eps 1e-5): R = inv1*rsqrt(var2+1e-5)
// F32IN: read fp32 x, also write h = bf16(x); stats on bf16-rounded values.
template<bool DBL, bool F32IN>
__global__ __launch_bounds__(256) void stats_kernel(const void* __restrict__ xv,
                                                    bf16_t* __restrict__ hout,
                                                    float2* __restrict__ st) {
    int row  = blockIdx.x * 4 + (threadIdx.x >> 6);
    int lane = threadIdx.x & 63;
    float vals[16];
    if (F32IN) {
        const float* xr = (const float*)xv + (long)row * DIM + lane * 16;
        float4 a0 = *(const float4*)(xr);
        float4 a1 = *(const float4*)(xr + 4);
        float4 a2 = *(const float4*)(xr + 8);
        float4 a3 = *(const float4*)(xr + 12);
        float raw[16] = {a0.x,a0.y,a0.z,a0.w, a1.x,a1.y,a1.z,a1.w,
                         a2.x,a2.y,a2.z,a2.w, a3.x,a3.y,a3.z,a3.w};
        us8 o0, o1;
        #pragma unroll
        for (int j = 0; j < 8; ++j) { o0[j] = f2bfu(raw[j]); o1[j] = f2bfu(raw[8+j]); }
        *(us8*)(hout + (long)row * DIM + lane * 16)     = o0;
        *(us8*)(hout + (long)row * DIM + lane * 16 + 8) = o1;
        #pragma unroll
        for (int j = 0; j < 8; ++j) {
            vals[j]     = (float)__builtin_bit_cast(bf16_t, o0[j]);
            vals[8 + j] = (float)__builtin_bit_cast(bf16_t, o1[j]);
        }
    } else {
        const bf16_t* xr = (const bf16_t*)xv + (long)row * DIM + lane * 16;
        bf16x8 a = *(const bf16x8*)xr;
        bf16x8 c = *(const bf16x8*)(xr + 8);
        #pragma unroll
        for (int j = 0; j < 8; ++j) { vals[j] = (float)a[j]; vals[8 + j] = (float)c[j]; }
    }
    float s = 0.f;
    #pragma unroll
    for (int j = 0; j < 16; ++j) s += vals[j];
    #pragma unroll
    for (int off = 32; off > 0; off >>= 1) s += __shfl_xor(s, off);
    float mu = s * (1.0f / DIM);
    float ss = 0.f;
    #pragma unroll
    for (int j = 0; j < 16; ++j) { float d = vals[j] - mu; ss += d * d; }
    #pragma unroll
    for (int off = 32; off > 0; off >>= 1) ss += __shfl_xor(ss, off);
    if (lane == 0) {
        float var = ss * (1.0f / DIM);
        float R;
        if (DBL) {
            float inv1 = 1.0f / sqrtf(var + 1e-6f);
            float var2 = var * inv1 * inv1;
            R = inv1 * (1.0f / sqrtf(var2 + 1e-5f));
        } else {
            R = 1.0f / sqrtf(var + 1e-5f);
        }
        st[row] = float2{mu, R};
    }
}

// ---------------- block-wide sum helper retained for attn ----------------

// ---------------- 32x32x16 MFMA GEMM + optional tx-tail blocks
// 1D grid: bid < gemmBlocks -> GEMM tile; else transpose next layer's weight.
// EPI: 0 = LN-folded qkv (v = R*acc - R*mu*c1 + c2),
//      1 = +bias +resid(bf16),
//      2 = LN-folded ff1 (v = R*acc - R*mu*c1 + c2 + b1 then gelu).
template<int BM, int BN, int WM, int WN, int EPI>
__global__ __launch_bounds__(256) void gemm32(
    const bf16_t* __restrict__ A, const bf16_t* __restrict__ BT,
    const float* __restrict__ bias, const bf16_t* __restrict__ resid,
    bf16_t* __restrict__ Ch,
    const float2* __restrict__ stats,
    const float* __restrict__ c1, const float* __restrict__ c2,
    int N, int K, int gemmBlocks, int gx,
    const float* __restrict__ txsrc, bf16_t* __restrict__ txdst,
    int txK, int txN,
    const float* __restrict__ txg, const float* __restrict__ txb,
    float* __restrict__ txc1, float* __restrict__ txc2)
{
    constexpr int WAVES_N = BN / WN;
    constexpr int FM = WM / 32, FN = WN / 32;
    constexpr int NSTG = BM / 32 + BN / 32;

    __shared__ bf16_t As[2][BM * 64];
    __shared__ bf16_t Bs[2][BN * 64];

    int bid = blockIdx.x;
    if (bid >= gemmBlocks) {
        tx_chunks4(txsrc, txdst, txK, txN, bid - gemmBlocks, txg, txb, txc1, txc2);
        return;
    }
    int bx = bid % gx, by = bid / gx;

    int tid  = threadIdx.x;
    int wave = tid >> 6, lane = tid & 63;
    int wr = wave / WAVES_N, wc = wave % WAVES_N;
    int m0 = by * BM, n0 = bx * BN;

    f32x16 acc[FM][FN];
    #pragma unroll
    for (int m = 0; m < FM; ++m)
        #pragma unroll
        for (int n = 0; n < FN; ++n)
            #pragma unroll
            for (int r = 0; r < 16; ++r)
                acc[m][n][r] = 0.f;

    long rsb = (long)K * 2;                  // row byte stride (A)
    int  lr  = lane & 31;
    int  lkb = (lane >> 5) * 16;
    int  nkb = K >> 6;

    const char* Abase = (const char*)A + (long)(m0 + lr) * rsb + lkb;
    const char* Bbase = (const char*)BT + (long)(n0 >> 5) * nkb * 4096 + lane * 16;

    auto stage = [&](int c, int t) {
        long kb = (long)t * 128;             // t*64 k * 2B (A side)
        #pragma unroll
        for (int i = 0; i < BM / 32; ++i) {
            int b = i * 4 + wave;
            gload_lds16(Abase + (long)(b >> 2) * 32 * rsb + (b & 3) * 32 + kb,
                        (char*)&As[c][0] + b * 1024);
        }
        #pragma unroll
        for (int i = 0; i < BN / 32; ++i) {
            int b = i * 4 + wave;            // s = b>>2, kk = b&3
            gload_lds16(Bbase + ((long)(b >> 2) * nkb + t) * 4096 + (b & 3) * 1024,
                        (char*)&Bs[c][0] + b * 1024);
        }
    };

    int nt = K >> 6;
    stage(0, 0);
    int cur = 0;
    for (int t = 0; t < nt; ++t) {
        if (t + 1 < nt) {
            stage(cur ^ 1, t + 1);
            asm volatile("s_waitcnt vmcnt(%c0)" :: "i"(NSTG) : "memory");
        } else {
            asm volatile("s_waitcnt vmcnt(0)" ::: "memory");
        }
        __builtin_amdgcn_s_barrier();
        asm volatile("" ::: "memory");
        bf16x8 af[FM][4], bq[FN][4];
        #pragma unroll
        for (int m = 0; m < FM; ++m)
            #pragma unroll
            for (int kk = 0; kk < 4; ++kk)
                af[m][kk] = *(const bf16x8*)((const char*)&As[cur][0] +
                            ((wr * FM + m) * 4 + kk) * 1024 + (lane << 4));
        #pragma unroll
        for (int n = 0; n < FN; ++n)
            #pragma unroll
            for (int kk = 0; kk < 4; ++kk)
                bq[n][kk] = *(const bf16x8*)((const char*)&Bs[cur][0] +
                            ((wc * FN + n) * 4 + kk) * 1024 + (lane << 4));
        #pragma unroll
        for (int kk = 0; kk < 4; ++kk)
            #pragma unroll
            for (int m = 0; m < FM; ++m)
                #pragma unroll
                for (int n = 0; n < FN; ++n)
                    acc[m][n] = __builtin_amdgcn_mfma_f32_32x32x16_bf16(
                        af[m][kk], bq[n][kk], acc[m][n], 0, 0, 0);
        asm volatile("" ::: "memory");
        __builtin_amdgcn_s_barrier();
        cur ^= 1;
    }

    // C/D layout: col = lane&31, row = (reg&3) + 8*(reg>>2) + 4*(lane>>5)
    int rbase = 4 * (lane >> 5);
    #pragma unroll
    for (int m = 0; m < FM; ++m) {
        #pragma unroll
        for (int n = 0; n < FN; ++n) {
            int colI = n0 + wc * WN + n * 32 + (lane & 31);
            float cc1 = 0.f, cc2 = 0.f, bb = 0.f;
            if (EPI == 0 || EPI == 2) { cc1 = c1[colI]; cc2 = c2[colI]; }
            if (EPI == 1 || EPI == 2) bb = bias[colI];
            #pragma unroll
            for (int r = 0; r < 16; ++r) {
                int rowI = m0 + wr * WM + m * 32 + rbase + (r & 3) + 8 * (r >> 2);
                float v = acc[m][n][r];
                long off = (long)rowI * N + colI;
                if (EPI == 1) {
                    v += bb + (float)resid[off];
                } else {
                    float2 stv = stats[rowI];
                    v = stv.y * v - stv.y * stv.x * cc1 + cc2 + bb;
                    if (EPI == 2)
                        v = 0.5f * v * (1.0f + erff(v * 0.70710678118654752f));
                }
                Ch[off] = (bf16_t)v;
            }
        }
    }
}

// ---------------- head GEMM: A bf16 [M][K] (row stride aStride), B fp32 [K][N]
__global__ __launch_bounds__(256) void gemm_hd(
    const bf16_t* __restrict__ A, const float* __restrict__ Bw,
    const float* __restrict__ bias, bf16_t* __restrict__ C,
    int N, int K, long aStride, long sA, long sB, long sbias, long sC)
{
    long g = blockIdx.z;
    A += g * sA;
    const float* Bp = Bw + g * sB;
    bias += g * sbias;
    bf16_t* Cp = C + g * sC;

    __shared__ bf16_t As[2][64 * 64];
    __shared__ float  Bf[2][64 * 64];

    int tid = threadIdx.x, wave = tid >> 6, lane = tid & 63;
    int wr = wave >> 1, wc = wave & 1;
    int n0 = blockIdx.x * 64;

    f32x4 acc[2][2];
    #pragma unroll
    for (int m = 0; m < 2; ++m)
        #pragma unroll
        for (int n = 0; n < 2; ++n)
            acc[m][n] = f32x4{0.f, 0.f, 0.f, 0.f};

    long rsb = aStride * 2;
    int  lr  = lane & 15;
    int  lkb = (lane >> 4) * 16;
    const char* Abase = (const char*)A + (long)lr * rsb + lkb;   // m0 = 0

    auto stage = [&](int c, int t) {
        long kb = (long)t * 128;
        #pragma unroll
        for (int i = 0; i < 2; ++i) {
            int b = i * 4 + wave;
            gload_lds16(Abase + (long)(b >> 1) * 16 * rsb + (b & 1) * 64 + kb,
                        (char*)&As[c][0] + b * 1024);
        }
        #pragma unroll
        for (int i = 0; i < 4; ++i) {
            int ch = i * 4 + wave;
            int row = ch * 4 + (lane >> 4);
            gload_lds16((const char*)Bp + ((long)(t * 64 + row) * N + n0) * 4 + (lane & 15) * 16,
                        (char*)&Bf[c][0] + ch * 1024);
        }
    };

    int nt = K >> 6;
    stage(0, 0);
    int cur = 0;
    for (int t = 0; t < nt; ++t) {
        if (t + 1 < nt) {
            stage(cur ^ 1, t + 1);
            asm volatile("s_waitcnt vmcnt(6)" ::: "memory");
        } else {
            asm volatile("s_waitcnt vmcnt(0)" ::: "memory");
        }
        __builtin_amdgcn_s_barrier();
        asm volatile("" ::: "memory");
        bf16x8 af[2][2], bq[2][2];
        #pragma unroll
        for (int m = 0; m < 2; ++m)
            #pragma unroll
            for (int h = 0; h < 2; ++h)
                af[m][h] = *(const bf16x8*)((const char*)&As[cur][0] +
                           ((wr * 2 + m) * 2 + h) * 1024 + (lane << 4));
        #pragma unroll
        for (int n = 0; n < 2; ++n) {
            int nl = wc * 32 + n * 16 + lr;
            #pragma unroll
            for (int h = 0; h < 2; ++h) {
                #pragma unroll
                for (int j = 0; j < 8; ++j) {
                    float v = Bf[cur][(h * 32 + (lane >> 4) * 8 + j) * 64 + nl];
                    bq[n][h][j] = (bf16_t)v;
                }
            }
        }
        #pragma unroll
        for (int h = 0; h < 2; ++h)
            #pragma unroll
            for (int m = 0; m < 2; ++m)
                #pragma unroll
                for (int n = 0; n < 2; ++n)
                    acc[m][n] = __builtin_amdgcn_mfma_f32_16x16x32_bf16(
                        af[m][h], bq[n][h], acc[m][n], 0, 0, 0);
        asm volatile("" ::: "memory");
        __builtin_amdgcn_s_barrier();
        cur ^= 1;
    }

    int lq = (lane >> 4) * 4;
    #pragma unroll
    for (int m = 0; m < 2; ++m) {
        #pragma unroll
        for (int n = 0; n < 2; ++n) {
            int colI = n0 + wc * 32 + n * 16 + lr;
            float bb = bias[colI];
            #pragma unroll
            for (int j = 0; j < 4; ++j) {
                int rowI = wr * 32 + m * 16 + lq + j;
                float v = fmaxf(acc[m][n][j] + bb, 0.0f);
                Cp[(long)rowI * N + colI] = (bf16_t)v;
            }
        }
    }
}

// ---------------- fused attention: one block per (batch, head). T=32, HD=64.
__global__ __launch_bounds__(256) void attn_kernel(const bf16_t* __restrict__ qkv,
                                                   bf16_t* __restrict__ o) {
    int bh = blockIdx.x;
    int b  = bh >> 4;
    int hh = bh & 15;
    __shared__ float qs[32][65];
    __shared__ float kt[64][36];
    __shared__ float vs[32][68];
    __shared__ float ps[32][33];
    const bf16_t* base = qkv + (long)b * SEQ * (3 * DIM) + hh * HDIM;
    int tid = threadIdx.x;

    {
        int t = tid >> 3, c = (tid & 7) * 8;
        bf16x8 qv = *(const bf16x8*)(base + (long)t * 3 * DIM + c);
        bf16x8 kv = *(const bf16x8*)(base + (long)t * 3 * DIM + DIM + c);
        bf16x8 vv = *(const bf16x8*)(base + (long)t * 3 * DIM + 2 * DIM + c);
        #pragma unroll
        for (int j = 0; j < 8; ++j) {
            int d = c + j;
            qs[t][d] = (float)qv[j];
            kt[d][(((t >> 2) ^ ((d >> 2) & 7)) << 2) + (t & 3)] = (float)kv[j];
            vs[t][d] = (float)vv[j];
        }
    }
    __syncthreads();

    {
        int r  = tid >> 3;
        int c0 = (tid & 7) * 4;
        f32x4 acc = {0.f, 0.f, 0.f, 0.f};
        #pragma unroll
        for (int d = 0; d < 64; ++d) {
            float qv = qs[r][d];
            float4 kv = *(const float4*)&kt[d][(((c0 >> 2) ^ ((d >> 2) & 7)) << 2)];
            acc[0] = fmaf(qv, kv.x, acc[0]);
            acc[1] = fmaf(qv, kv.y, acc[1]);
            acc[2] = fmaf(qv, kv.z, acc[2]);
            acc[3] = fmaf(qv, kv.w, acc[3]);
        }
        #pragma unroll
        for (int i = 0; i < 4; ++i) ps[r][c0 + i] = acc[i] * 0.125f;
    }
    __syncthreads();

    if (tid < 32) {
        float mx = -1e30f;
        for (int c = 0; c < 32; ++c) mx = fmaxf(mx, ps[tid][c]);
        float sum = 0.f;
        for (int c = 0; c < 32; ++c) { float e = expf(ps[tid][c] - mx); ps[tid][c] = e; sum += e; }
        float inv = 1.f / sum;
        for (int c = 0; c < 32; ++c) ps[tid][c] *= inv;
    }
    __syncthreads();

    {
        int r  = tid >> 3;
        int d0 = (tid & 7) * 8;
        float acc[8] = {};
        #pragma unroll
        for (int c = 0; c < 32; ++c) {
            float pv = ps[r][c];
            float4 v0 = *(const float4*)&vs[c][d0];
            float4 v1 = *(const float4*)&vs[c][d0 + 4];
            acc[0] = fmaf(pv, v0.x, acc[0]);
            acc[1] = fmaf(pv, v0.y, acc[1]);
            acc[2] = fmaf(pv, v0.z, acc[2]);
            acc[3] = fmaf(pv, v0.w, acc[3]);
            acc[4] = fmaf(pv, v1.x, acc[4]);
            acc[5] = fmaf(pv, v1.y, acc[5]);
            acc[6] = fmaf(pv, v1.z, acc[6]);
            acc[7] = fmaf(pv, v1.w, acc[7]);
        }
        us8 ov;
        #pragma unroll
        for (int j = 0; j < 8; ++j) ov[j] = f2bfu(acc[j]);
        *(us8*)(o + (long)b * SEQ * DIM + (long)r * DIM + hh * HDIM + d0) = ov;
    }
}

// ---------------- head layer 3: one wave per (n, b), dot-512
__global__ __launch_bounds__(256) void head3_kernel(const bf16_t* __restrict__ h2,
                                                    const float* __restrict__ w3,
                                                    const float* __restrict__ b3,
                                                    float* __restrict__ out) {
    int gid  = blockIdx.x * 256 + threadIdx.x;
    int wave = gid >> 6;
    int lane = gid & 63;
    if (wave >= NHEAD_OUT * BATCH) return;
    int n = wave >> 6;
    int b = wave & 63;
    const bf16_t* a = h2 + ((long)n * BATCH + b) * IDH;
    const float*  w = w3 + (long)n * IDH;
    float acc = 0.f;
    #pragma unroll
    for (int i = lane; i < IDH; i += 64) acc = fmaf((float)a[i], w[i], acc);
    #pragma unroll
    for (int off = 32; off > 0; off >>= 1) acc += __shfl_down(acc, off);
    if (lane == 0) out[b * NHEAD_OUT + n] = acc + b3[n];
}

extern "C" void kernel_launch(void* const* d_in, const int* in_sizes, int n_in,
                              void* d_out, int out_size, void* d_ws, size_t ws_size,
                              hipStream_t stream) {
    const float* x      = (const float*)d_in[0];
    const float* qkv_w  = (const float*)d_in[1];
    const float* out_w  = (const float*)d_in[2];
    const float* out_b  = (const float*)d_in[3];
    const float* attn_g = (const float*)d_in[4];
    const float* attn_b = (const float*)d_in[5];
    const float* ff_g   = (const float*)d_in[6];
    const float* ff_b   = (const float*)d_in[7];
    const float* ff_w1  = (const float*)d_in[8];
    const float* ff_b1  = (const float*)d_in[9];
    const float* ff_w2  = (const float*)d_in[10];
    const float* ff_b2  = (const float*)d_in[11];
    const float* hw1    = (const float*)d_in[12];
    const float* hb1    = (const float*)d_in[13];
    const float* hw2    = (const float*)d_in[14];
    const float* hb2    = (const float*)d_in[15];
    const float* hw3    = (const float*)d_in[16];
    const float* hb3    = (const float*)d_in[17];
    float* out = (float*)d_out;

    char* p = (char*)d_ws;
    bf16_t* h     = (bf16_t*)p;           p += (long)TOK * DIM * 2;
    bf16_t* qkvb  = (bf16_t*)p;           p += (long)TOK * 3 * DIM * 2;
    bf16_t* ob    = (bf16_t*)p;           p += (long)TOK * DIM * 2;
    bf16_t* ffb   = (bf16_t*)p;           p += (long)TOK * FFD * 2;
    bf16_t* h1    = (bf16_t*)p;           p += (long)NHEAD_OUT * BATCH * IDH * 2;
    bf16_t* h2    = (bf16_t*)p;           p += (long)NHEAD_OUT * BATCH * IDH * 2;
    bf16_t* qkvwt = (bf16_t*)p;           p += (long)LAYERS * DIM * 3 * DIM * 2;
    bf16_t* outwt = (bf16_t*)p;           p += (long)LAYERS * DIM * DIM * 2;
    bf16_t* ff1t  = (bf16_t*)p;           p += (long)LAYERS * DIM * FFD * 2;
    bf16_t* ff2t  = (bf16_t*)p;           p += (long)LAYERS * FFD * DIM * 2;
    float2* stQ   = (float2*)p;           p += (long)TOK * 8;
    float2* stF   = (float2*)p;           p += (long)TOK * 8;
    float*  cbuf  = (float*)p;
    float*  c1q   = cbuf;                              // L * 3*DIM
    float*  c2q   = c1q + (long)LAYERS * 3 * DIM;
    float*  c1f   = c2q + (long)LAYERS * 3 * DIM;      // L * FFD
    float*  c2f   = c1f + (long)LAYERS * FFD;
    size_t  cbytes = ((long)LAYERS * (3 * DIM + 3 * DIM + FFD + FFD)) * 4;

    const long sQ = (long)DIM * 3 * DIM;
    const long sO = (long)DIM * DIM;
    const long sF1 = (long)DIM * FFD;
    const long sF2 = (long)FFD * DIM;
    const int tbQ  = (3 * DIM / 32) * (DIM / 64) / 4;   // 384
    const int tbO  = (DIM / 32) * (DIM / 64) / 4;       // 128
    const int tbF1 = (FFD / 32) * (DIM / 64) / 4;       // 256
    const int tbF2 = (DIM / 32) * (FFD / 64) / 4;       // 256

    // zero the c1/c2 accumulators (accumulated via atomics every call)
    hipMemsetAsync(cbuf, 0, cbytes, stream);

    // ---- upfront: layer-0 weights ----
    TxPack tp;
    tp.src[0] = qkv_w; tp.dst[0] = qkvwt; tp.K[0] = DIM; tp.N[0] = 3 * DIM;
    tp.g[0] = attn_g; tp.b[0] = attn_b; tp.c1[0] = c1q; tp.c2[0] = c2q;
    tp.src[1] = out_w; tp.dst[1] = outwt; tp.K[1] = DIM; tp.N[1] = DIM;
    tp.g[1] = nullptr; tp.b[1] = nullptr; tp.c1[1] = nullptr; tp.c2[1] = nullptr;
    tp.src[2] = ff_w1; tp.dst[2] = ff1t;  tp.K[2] = DIM; tp.N[2] = FFD;
    tp.g[2] = ff_g; tp.b[2] = ff_b; tp.c1[2] = c1f; tp.c2[2] = c2f;
    tp.src[3] = ff_w2; tp.dst[3] = ff2t;  tp.K[3] = FFD; tp.N[3] = DIM;
    tp.g[3] = nullptr; tp.b[3] = nullptr; tp.c1[3] = nullptr; tp.c2[3] = nullptr;
    tp.blk0[0] = 0;
    tp.blk0[1] = tbQ;
    tp.blk0[2] = tbQ + tbO;
    tp.blk0[3] = tbQ + tbO + tbF1;
    txd<<<tbQ + tbO + tbF1 + tbF2, 256, 0, stream>>>(tp);

    for (int l = 0; l < LAYERS; ++l) {
        bool more = (l + 1 < LAYERS);
        int ln = more ? (l + 1) : l;   // tail pointers (unused when !more)

        if (l == 0)
            stats_kernel<true, true><<<TOK / 4, 256, 0, stream>>>(x, h, stQ);
        else
            stats_kernel<true, false><<<TOK / 4, 256, 0, stream>>>(h, nullptr, stQ);

        // qkv (LN folded) + next-layer qkv_w tx tail
        {
            int gx = 3 * DIM / 128, gb = gx * (TOK / 64);
            gemm32<64, 128, 32, 64, 0><<<gb + (more ? tbQ : 0), 256, 0, stream>>>(
                h, qkvwt + l * sQ, nullptr, nullptr, qkvb,
                stQ, c1q + l * 3 * DIM, c2q + l * 3 * DIM,
                3 * DIM, DIM, gb, gx,
                qkv_w + ln * sQ, qkvwt + ln * sQ, DIM, 3 * DIM,
                attn_g + ln * DIM, attn_b + ln * DIM,
                c1q + ln * 3 * DIM, c2q + ln * 3 * DIM);
        }
        attn_kernel<<<BATCH * NH, 256, 0, stream>>>(qkvb, ob);
        // out-proj + next out_w tx tail (unscaled)
        {
            int gx = DIM / 64, gb = gx * (TOK / 64);
            gemm32<64, 64, 32, 32, 1><<<gb + (more ? tbO : 0), 256, 0, stream>>>(
                ob, outwt + l * sO, out_b + l * DIM, h, h,
                nullptr, nullptr, nullptr,
                DIM, DIM, gb, gx,
                out_w + ln * sO, outwt + ln * sO, DIM, DIM,
                nullptr, nullptr, nullptr, nullptr);
        }
        stats_kernel<false, false><<<TOK / 4, 256, 0, stream>>>(h, nullptr, stF);
        // ff1 (LN folded + gelu) + next ff_w1 tx tail
        {
            int gx = FFD / 128, gb = gx * (TOK / 64);
            gemm32<64, 128, 32, 64, 2><<<gb + (more ? tbF1 : 0), 256, 0, stream>>>(
                h, ff1t + l * sF1, ff_b1 + l * FFD, nullptr, ffb,
                stF, c1f + l * FFD, c2f + l * FFD,
                FFD, DIM, gb, gx,
                ff_w1 + ln * sF1, ff1t + ln * sF1, DIM, FFD,
                ff_g + ln * DIM, ff_b + ln * DIM,
                c1f + ln * FFD, c2f + ln * FFD);
        }
        // ff2 + next ff_w2 tx tail (unscaled)
        {
            int gx = DIM / 64, gb = gx * (TOK / 64);
            gemm32<64, 64, 32, 32, 1><<<gb + (more ? tbF2 : 0), 256, 0, stream>>>(
                ffb, ff2t + l * sF2, ff_b2 + l * DIM, h, h,
                nullptr, nullptr, nullptr,
                DIM, FFD, gb, gx,
                ff_w2 + ln * sF2, ff2t + ln * sF2, FFD, DIM,
                nullptr, nullptr, nullptr, nullptr);
        }
    }

    // heads: head1 reads h directly (x_comb = first 2048 bf16 of each batch block)
    gemm_hd<<<dim3(IDH / 64, 1, NHEAD_OUT), 256, 0, stream>>>(
        h, hw1, hb1, h1,
        IDH, 2 * DIM, (long)SEQ * DIM,
        0, (long)2 * DIM * IDH, IDH, (long)BATCH * IDH);
    gemm_hd<<<dim3(IDH / 64, 1, NHEAD_OUT), 256, 0, stream>>>(
        h1, hw2, hb2, h2,
        IDH, IDH, IDH,
        (long)BATCH * IDH, (long)IDH * IDH, IDH, (long)BATCH * IDH);
    head3_kernel<<<(NHEAD_OUT * BATCH * 64) / 256, 256, 0, stream>>>(h2, hw3, hb3, out);
}

// Round 18
// 518.490 us; speedup vs baseline: 1.1635x; 1.1635x over previous
//
#include <hip/hip_runtime.h>
#include <math.h>

static constexpr int BATCH = 64;
static constexpr int SEQ   = 32;
static constexpr int TOK   = BATCH * SEQ;   // 2048
static constexpr int DIM   = 1024;
static constexpr int NH    = 16;
static constexpr int HDIM  = 64;
static constexpr int FFD   = 2048;
static constexpr int LAYERS= 4;
static constexpr int NHEAD_OUT = 26;
static constexpr int IDH   = 512;

typedef __bf16 bf16_t;
typedef __bf16 bf16x4 __attribute__((ext_vector_type(4)));
typedef __bf16 bf16x8 __attribute__((ext_vector_type(8)));
typedef float  f32x4  __attribute__((ext_vector_type(4)));
typedef float  f32x16 __attribute__((ext_vector_type(16)));
typedef unsigned short us4 __attribute__((ext_vector_type(4)));
typedef unsigned short us8 __attribute__((ext_vector_type(8)));

__device__ __forceinline__ unsigned short f2bfu(float f) {
    return __builtin_bit_cast(unsigned short, (bf16_t)f);
}

__device__ __forceinline__ void gload_lds16(const void* gp, void* lp) {
    __builtin_amdgcn_global_load_lds(
        (const __attribute__((address_space(1))) unsigned int*)gp,
        (__attribute__((address_space(3))) unsigned int*)lp,
        16, 0, 0);
}

// ---------------- fragment-tiled transpose: 4 chunks of ONE matrix ----------
// chunk (ns,kt) = 4KB: [kk(4)][lane(64)][16B]; lane l: n = ns*32+(l&31),
// k = kt*64 + kk*16 + (l>>5)*8 + j.
__device__ __forceinline__ void tx_chunks4(const float* __restrict__ src,
                                           bf16_t* __restrict__ dst,
                                           int K, int N, int base4) {
    int nkb = K >> 6;
    int kk = threadIdx.x >> 6;
    int l  = threadIdx.x & 63;
    int nl = l & 31, k8 = (l >> 5) * 8;
    int base = base4 * 4;
    #pragma unroll
    for (int q = 0; q < 4; ++q) {
        int chunk = base + q;
        int ns = chunk / nkb;
        int kt = chunk - ns * nkb;
        int n = ns * 32 + nl;
        int kb = kt * 64 + kk * 16 + k8;
        us8 o;
        #pragma unroll
        for (int j = 0; j < 8; ++j)
            o[j] = f2bfu(src[(long)(kb + j) * N + n]);
        *(us8*)(dst + (long)chunk * 2048 + kk * 512 + l * 8) = o;
    }
}

// ---------------- upfront transpose (layer-0 weights only) ----------------
struct TxPack {
    const float* src[4];
    bf16_t*      dst[4];
    int K[4], N[4];
    int blk0[4];
};

__global__ __launch_bounds__(256) void txd(TxPack p) {
    int bid = blockIdx.x;
    int s = 0;
    #pragma unroll
    for (int i = 1; i < 4; ++i) if (bid >= p.blk0[i]) s = i;
    tx_chunks4(p.src[s], p.dst[s], p.K[s], p.N[s], bid - p.blk0[s]);
}

// ---------------- block-wide sum (256 threads = 4 waves) ----------------
__device__ __forceinline__ float block_sum(float v, float* red) {
    #pragma unroll
    for (int off = 32; off > 0; off >>= 1) v += __shfl_down(v, off);
    int lane = threadIdx.x & 63;
    int w    = threadIdx.x >> 6;
    if (lane == 0) red[w] = v;
    __syncthreads();
    float t = red[0] + red[1] + red[2] + red[3];
    __syncthreads();
    return t;
}

// ---------------- LayerNorm -> bf16 output
// F32IN: input is fp32 x; also writes h = bf16(x) (layer-0 fusion of cvt).
template<bool PRE, bool F32IN>
__global__ __launch_bounds__(256) void ln_kernel(const void* __restrict__ xv,
                                                 const float* __restrict__ g,
                                                 const float* __restrict__ b,
                                                 bf16_t* __restrict__ y,
                                                 bf16_t* __restrict__ hout) {
    __shared__ float red[4];
    long row = blockIdx.x;
    int tid = threadIdx.x;
    float4 v;
    if (F32IN) {
        const float* xr = (const float*)xv + row * DIM;
        v = *(const float4*)(xr + tid * 4);
        us4 hc;
        hc.x = f2bfu(v.x); hc.y = f2bfu(v.y); hc.z = f2bfu(v.z); hc.w = f2bfu(v.w);
        *(us4*)(hout + row * DIM + tid * 4) = hc;
        v.x = (float)(bf16_t)v.x; v.y = (float)(bf16_t)v.y;
        v.z = (float)(bf16_t)v.z; v.w = (float)(bf16_t)v.w;
    } else {
        const bf16_t* xr = (const bf16_t*)xv + row * DIM;
        bf16x4 r4 = *(const bf16x4*)(xr + tid * 4);
        v.x = (float)r4[0]; v.y = (float)r4[1]; v.z = (float)r4[2]; v.w = (float)r4[3];
    }
    if (PRE) {
        float s  = block_sum(v.x + v.y + v.z + v.w, red);
        float mu = s * (1.0f / DIM);
        v.x -= mu; v.y -= mu; v.z -= mu; v.w -= mu;
        float ss = block_sum(v.x*v.x + v.y*v.y + v.z*v.z + v.w*v.w, red);
        float r  = 1.0f / sqrtf(ss * (1.0f / DIM) + 1e-6f);
        v.x *= r; v.y *= r; v.z *= r; v.w *= r;
    }
    float s  = block_sum(v.x + v.y + v.z + v.w, red);
    float mu = s * (1.0f / DIM);
    v.x -= mu; v.y -= mu; v.z -= mu; v.w -= mu;
    float ss = block_sum(v.x*v.x + v.y*v.y + v.z*v.z + v.w*v.w, red);
    float r  = 1.0f / sqrtf(ss * (1.0f / DIM) + 1e-5f);
    float4 gg = *(const float4*)(g + tid * 4);
    float4 bb = *(const float4*)(b + tid * 4);
    us4 o;
    o.x = f2bfu(v.x * r * gg.x + bb.x);
    o.y = f2bfu(v.y * r * gg.y + bb.y);
    o.z = f2bfu(v.z * r * gg.z + bb.z);
    o.w = f2bfu(v.w * r * gg.w + bb.w);
    *(us4*)(y + row * DIM + tid * 4) = o;
}

// ---------------- 32x32x16 MFMA GEMM + optional tx-tail blocks
// 1D grid: bid < gemmBlocks -> GEMM tile (bx=bid%gx, by=bid/gx);
// else -> transpose 4 chunks of NEXT layer's weight (rides along, ordering
// guaranteed by kernel boundary before the consumer launch).
// EPI: 0 = none, 1 = +bias +resid(bf16), 2 = +bias gelu. All bf16 out.
template<int BM, int BN, int WM, int WN, int EPI>
__global__ __launch_bounds__(256) void gemm32(
    const bf16_t* __restrict__ A, const bf16_t* __restrict__ BT,
    const float* __restrict__ bias, const bf16_t* __restrict__ resid,
    bf16_t* __restrict__ Ch,
    int N, int K, int gemmBlocks, int gx,
    const float* __restrict__ txsrc, bf16_t* __restrict__ txdst,
    int txK, int txN)
{
    constexpr int WAVES_N = BN / WN;
    constexpr int FM = WM / 32, FN = WN / 32;
    constexpr int NSTG = BM / 32 + BN / 32;

    __shared__ bf16_t As[2][BM * 64];
    __shared__ bf16_t Bs[2][BN * 64];

    int bid = blockIdx.x;
    if (bid >= gemmBlocks) {
        tx_chunks4(txsrc, txdst, txK, txN, bid - gemmBlocks);
        return;
    }
    int bx = bid % gx, by = bid / gx;

    int tid  = threadIdx.x;
    int wave = tid >> 6, lane = tid & 63;
    int wr = wave / WAVES_N, wc = wave % WAVES_N;
    int m0 = by * BM, n0 = bx * BN;

    f32x16 acc[FM][FN];
    #pragma unroll
    for (int m = 0; m < FM; ++m)
        #pragma unroll
        for (int n = 0; n < FN; ++n)
            #pragma unroll
            for (int r = 0; r < 16; ++r)
                acc[m][n][r] = 0.f;

    long rsb = (long)K * 2;                  // row byte stride (A)
    int  lr  = lane & 31;
    int  lkb = (lane >> 5) * 16;
    int  nkb = K >> 6;

    const char* Abase = (const char*)A + (long)(m0 + lr) * rsb + lkb;
    const char* Bbase = (const char*)BT + (long)(n0 >> 5) * nkb * 4096 + lane * 16;

    auto stage = [&](int c, int t) {
        long kb = (long)t * 128;             // t*64 k * 2B (A side)
        #pragma unroll
        for (int i = 0; i < BM / 32; ++i) {
            int b = i * 4 + wave;
            gload_lds16(Abase + (long)(b >> 2) * 32 * rsb + (b & 3) * 32 + kb,
                        (char*)&As[c][0] + b * 1024);
        }
        #pragma unroll
        for (int i = 0; i < BN / 32; ++i) {
            int b = i * 4 + wave;            // s = b>>2, kk = b&3
            gload_lds16(Bbase + ((long)(b >> 2) * nkb + t) * 4096 + (b & 3) * 1024,
                        (char*)&Bs[c][0] + b * 1024);
        }
    };

    int nt = K >> 6;
    stage(0, 0);
    int cur = 0;
    for (int t = 0; t < nt; ++t) {
        if (t + 1 < nt) {
            stage(cur ^ 1, t + 1);
            asm volatile("s_waitcnt vmcnt(%c0)" :: "i"(NSTG) : "memory");
        } else {
            asm volatile("s_waitcnt vmcnt(0)" ::: "memory");
        }
        __builtin_amdgcn_s_barrier();
        asm volatile("" ::: "memory");
        bf16x8 af[FM][4], bq[FN][4];
        #pragma unroll
        for (int m = 0; m < FM; ++m)
            #pragma unroll
            for (int kk = 0; kk < 4; ++kk)
                af[m][kk] = *(const bf16x8*)((const char*)&As[cur][0] +
                            ((wr * FM + m) * 4 + kk) * 1024 + (lane << 4));
        #pragma unroll
        for (int n = 0; n < FN; ++n)
            #pragma unroll
            for (int kk = 0; kk < 4; ++kk)
                bq[n][kk] = *(const bf16x8*)((const char*)&Bs[cur][0] +
                            ((wc * FN + n) * 4 + kk) * 1024 + (lane << 4));
        #pragma unroll
        for (int kk = 0; kk < 4; ++kk)
            #pragma unroll
            for (int m = 0; m < FM; ++m)
                #pragma unroll
                for (int n = 0; n < FN; ++n)
                    acc[m][n] = __builtin_amdgcn_mfma_f32_32x32x16_bf16(
                        af[m][kk], bq[n][kk], acc[m][n], 0, 0, 0);
        asm volatile("" ::: "memory");
        __builtin_amdgcn_s_barrier();
        cur ^= 1;
    }

    // C/D layout: col = lane&31, row = (reg&3) + 8*(reg>>2) + 4*(lane>>5)
    int rbase = 4 * (lane >> 5);
    #pragma unroll
    for (int m = 0; m < FM; ++m) {
        #pragma unroll
        for (int n = 0; n < FN; ++n) {
            int colI = n0 + wc * WN + n * 32 + (lane & 31);
            float bb = (EPI != 0) ? bias[colI] : 0.f;
            #pragma unroll
            for (int r = 0; r < 16; ++r) {
                int rowI = m0 + wr * WM + m * 32 + rbase + (r & 3) + 8 * (r >> 2);
                float v = acc[m][n][r] + bb;
                if (EPI == 2) v = 0.5f * v * (1.0f + erff(v * 0.70710678118654752f));
                long off = (long)rowI * N + colI;
                if (EPI == 1) v += (float)resid[off];
                Ch[off] = (bf16_t)v;
            }
        }
    }
}

// ---------------- head GEMM: A bf16 [M][K] (row stride aStride), B fp32 [K][N]
__global__ __launch_bounds__(256) void gemm_hd(
    const bf16_t* __restrict__ A, const float* __restrict__ Bw,
    const float* __restrict__ bias, bf16_t* __restrict__ C,
    int N, int K, long aStride, long sA, long sB, long sbias, long sC)
{
    long g = blockIdx.z;
    A += g * sA;
    const float* Bp = Bw + g * sB;
    bias += g * sbias;
    bf16_t* Cp = C + g * sC;

    __shared__ bf16_t As[2][64 * 64];
    __shared__ float  Bf[2][64 * 64];

    int tid = threadIdx.x, wave = tid >> 6, lane = tid & 63;
    int wr = wave >> 1, wc = wave & 1;
    int n0 = blockIdx.x * 64;

    f32x4 acc[2][2];
    #pragma unroll
    for (int m = 0; m < 2; ++m)
        #pragma unroll
        for (int n = 0; n < 2; ++n)
            acc[m][n] = f32x4{0.f, 0.f, 0.f, 0.f};

    long rsb = aStride * 2;                  // A row byte stride
    int  lr  = lane & 15;
    int  lkb = (lane >> 4) * 16;
    const char* Abase = (const char*)A + (long)lr * rsb + lkb;   // m0 = 0

    auto stage = [&](int c, int t) {
        long kb = (long)t * 128;
        #pragma unroll
        for (int i = 0; i < 2; ++i) {            // A: 64x64 bf16, fragment-ordered
            int b = i * 4 + wave;
            gload_lds16(Abase + (long)(b >> 1) * 16 * rsb + (b & 1) * 64 + kb,
                        (char*)&As[c][0] + b * 1024);
        }
        #pragma unroll
        for (int i = 0; i < 4; ++i) {            // B: 64k x 64n fp32 row-major
            int ch = i * 4 + wave;
            int row = ch * 4 + (lane >> 4);
            gload_lds16((const char*)Bp + ((long)(t * 64 + row) * N + n0) * 4 + (lane & 15) * 16,
                        (char*)&Bf[c][0] + ch * 1024);
        }
    };

    int nt = K >> 6;
    stage(0, 0);
    int cur = 0;
    for (int t = 0; t < nt; ++t) {
        if (t + 1 < nt) {
            stage(cur ^ 1, t + 1);
            asm volatile("s_waitcnt vmcnt(6)" ::: "memory");
        } else {
            asm volatile("s_waitcnt vmcnt(0)" ::: "memory");
        }
        __builtin_amdgcn_s_barrier();
        asm volatile("" ::: "memory");
        bf16x8 af[2][2], bq[2][2];
        #pragma unroll
        for (int m = 0; m < 2; ++m)
            #pragma unroll
            for (int h = 0; h < 2; ++h)
                af[m][h] = *(const bf16x8*)((const char*)&As[cur][0] +
                           ((wr * 2 + m) * 2 + h) * 1024 + (lane << 4));
        #pragma unroll
        for (int n = 0; n < 2; ++n) {
            int nl = wc * 32 + n * 16 + lr;
            #pragma unroll
            for (int h = 0; h < 2; ++h) {
                #pragma unroll
                for (int j = 0; j < 8; ++j) {
                    float v = Bf[cur][(h * 32 + (lane >> 4) * 8 + j) * 64 + nl];
                    bq[n][h][j] = (bf16_t)v;
                }
            }
        }
        #pragma unroll
        for (int h = 0; h < 2; ++h)
            #pragma unroll
            for (int m = 0; m < 2; ++m)
                #pragma unroll
                for (int n = 0; n < 2; ++n)
                    acc[m][n] = __builtin_amdgcn_mfma_f32_16x16x32_bf16(
                        af[m][h], bq[n][h], acc[m][n], 0, 0, 0);
        asm volatile("" ::: "memory");
        __builtin_amdgcn_s_barrier();
        cur ^= 1;
    }

    int lq = (lane >> 4) * 4;
    #pragma unroll
    for (int m = 0; m < 2; ++m) {
        #pragma unroll
        for (int n = 0; n < 2; ++n) {
            int colI = n0 + wc * 32 + n * 16 + lr;
            float bb = bias[colI];
            #pragma unroll
            for (int j = 0; j < 4; ++j) {
                int rowI = wr * 32 + m * 16 + lq + j;
                float v = fmaxf(acc[m][n][j] + bb, 0.0f);
                Cp[(long)rowI * N + colI] = (bf16_t)v;
            }
        }
    }
}

// ---------------- fused attention: one block per (batch, head). T=32, HD=64.
__global__ __launch_bounds__(256) void attn_kernel(const bf16_t* __restrict__ qkv,
                                                   bf16_t* __restrict__ o) {
    int bh = blockIdx.x;
    int b  = bh >> 4;
    int hh = bh & 15;
    __shared__ float qs[32][65];
    __shared__ float kt[64][36];
    __shared__ float vs[32][68];
    __shared__ float ps[32][33];
    const bf16_t* base = qkv + (long)b * SEQ * (3 * DIM) + hh * HDIM;
    int tid = threadIdx.x;

    {
        int t = tid >> 3, c = (tid & 7) * 8;
        bf16x8 qv = *(const bf16x8*)(base + (long)t * 3 * DIM + c);
        bf16x8 kv = *(const bf16x8*)(base + (long)t * 3 * DIM + DIM + c);
        bf16x8 vv = *(const bf16x8*)(base + (long)t * 3 * DIM + 2 * DIM + c);
        #pragma unroll
        for (int j = 0; j < 8; ++j) {
            int d = c + j;
            qs[t][d] = (float)qv[j];
            kt[d][(((t >> 2) ^ ((d >> 2) & 7)) << 2) + (t & 3)] = (float)kv[j];
            vs[t][d] = (float)vv[j];
        }
    }
    __syncthreads();

    {
        int r  = tid >> 3;
        int c0 = (tid & 7) * 4;
        f32x4 acc = {0.f, 0.f, 0.f, 0.f};
        #pragma unroll
        for (int d = 0; d < 64; ++d) {
            float qv = qs[r][d];
            float4 kv = *(const float4*)&kt[d][(((c0 >> 2) ^ ((d >> 2) & 7)) << 2)];
            acc[0] = fmaf(qv, kv.x, acc[0]);
            acc[1] = fmaf(qv, kv.y, acc[1]);
            acc[2] = fmaf(qv, kv.z, acc[2]);
            acc[3] = fmaf(qv, kv.w, acc[3]);
        }
        #pragma unroll
        for (int i = 0; i < 4; ++i) ps[r][c0 + i] = acc[i] * 0.125f;
    }
    __syncthreads();

    if (tid < 32) {
        float mx = -1e30f;
        for (int c = 0; c < 32; ++c) mx = fmaxf(mx, ps[tid][c]);
        float sum = 0.f;
        for (int c = 0; c < 32; ++c) { float e = expf(ps[tid][c] - mx); ps[tid][c] = e; sum += e; }
        float inv = 1.f / sum;
        for (int c = 0; c < 32; ++c) ps[tid][c] *= inv;
    }
    __syncthreads();

    {
        int r  = tid >> 3;
        int d0 = (tid & 7) * 8;
        float acc[8] = {};
        #pragma unroll
        for (int c = 0; c < 32; ++c) {
            float pv = ps[r][c];
            float4 v0 = *(const float4*)&vs[c][d0];
            float4 v1 = *(const float4*)&vs[c][d0 + 4];
            acc[0] = fmaf(pv, v0.x, acc[0]);
            acc[1] = fmaf(pv, v0.y, acc[1]);
            acc[2] = fmaf(pv, v0.z, acc[2]);
            acc[3] = fmaf(pv, v0.w, acc[3]);
            acc[4] = fmaf(pv, v1.x, acc[4]);
            acc[5] = fmaf(pv, v1.y, acc[5]);
            acc[6] = fmaf(pv, v1.z, acc[6]);
            acc[7] = fmaf(pv, v1.w, acc[7]);
        }
        us8 ov;
        #pragma unroll
        for (int j = 0; j < 8; ++j) ov[j] = f2bfu(acc[j]);
        *(us8*)(o + (long)b * SEQ * DIM + (long)r * DIM + hh * HDIM + d0) = ov;
    }
}

// ---------------- head layer 3: one wave per (n, b), dot-512
__global__ __launch_bounds__(256) void head3_kernel(const bf16_t* __restrict__ h2,
                                                    const float* __restrict__ w3,
                                                    const float* __restrict__ b3,
                                                    float* __restrict__ out) {
    int gid  = blockIdx.x * 256 + threadIdx.x;
    int wave = gid >> 6;
    int lane = gid & 63;
    if (wave >= NHEAD_OUT * BATCH) return;
    int n = wave >> 6;
    int b = wave & 63;
    const bf16_t* a = h2 + ((long)n * BATCH + b) * IDH;
    const float*  w = w3 + (long)n * IDH;
    float acc = 0.f;
    #pragma unroll
    for (int i = lane; i < IDH; i += 64) acc = fmaf((float)a[i], w[i], acc);
    #pragma unroll
    for (int off = 32; off > 0; off >>= 1) acc += __shfl_down(acc, off);
    if (lane == 0) out[b * NHEAD_OUT + n] = acc + b3[n];
}

extern "C" void kernel_launch(void* const* d_in, const int* in_sizes, int n_in,
                              void* d_out, int out_size, void* d_ws, size_t ws_size,
                              hipStream_t stream) {
    const float* x      = (const float*)d_in[0];
    const float* qkv_w  = (const float*)d_in[1];
    const float* out_w  = (const float*)d_in[2];
    const float* out_b  = (const float*)d_in[3];
    const float* attn_g = (const float*)d_in[4];
    const float* attn_b = (const float*)d_in[5];
    const float* ff_g   = (const float*)d_in[6];
    const float* ff_b   = (const float*)d_in[7];
    const float* ff_w1  = (const float*)d_in[8];
    const float* ff_b1  = (const float*)d_in[9];
    const float* ff_w2  = (const float*)d_in[10];
    const float* ff_b2  = (const float*)d_in[11];
    const float* hw1    = (const float*)d_in[12];
    const float* hb1    = (const float*)d_in[13];
    const float* hw2    = (const float*)d_in[14];
    const float* hb2    = (const float*)d_in[15];
    const float* hw3    = (const float*)d_in[16];
    const float* hb3    = (const float*)d_in[17];
    float* out = (float*)d_out;

    char* p = (char*)d_ws;
    bf16_t* h     = (bf16_t*)p;           p += (long)TOK * DIM * 2;
    bf16_t* qkvb  = (bf16_t*)p;           p += (long)TOK * 3 * DIM * 2;
    bf16_t* y     = (bf16_t*)p;           p += (long)TOK * DIM * 2;
    bf16_t* ob    = (bf16_t*)p;           p += (long)TOK * DIM * 2;
    bf16_t* ffb   = (bf16_t*)p;           p += (long)TOK * FFD * 2;
    bf16_t* h1    = (bf16_t*)p;           p += (long)NHEAD_OUT * BATCH * IDH * 2;
    bf16_t* h2    = (bf16_t*)p;           p += (long)NHEAD_OUT * BATCH * IDH * 2;
    bf16_t* qkvwt = (bf16_t*)p;           p += (long)LAYERS * DIM * 3 * DIM * 2;
    bf16_t* outwt = (bf16_t*)p;           p += (long)LAYERS * DIM * DIM * 2;
    bf16_t* ff1t  = (bf16_t*)p;           p += (long)LAYERS * DIM * FFD * 2;
    bf16_t* ff2t  = (bf16_t*)p;           p += (long)LAYERS * FFD * DIM * 2;

    // per-layer weight strides (elements)
    const long sQ = (long)DIM * 3 * DIM;
    const long sO = (long)DIM * DIM;
    const long sF1 = (long)DIM * FFD;
    const long sF2 = (long)FFD * DIM;
    // tx tail blocks per matrix (4 chunks/block)
    const int tbQ  = (3 * DIM / 32) * (DIM / 64) / 4;   // 384
    const int tbO  = (DIM / 32) * (DIM / 64) / 4;       // 128
    const int tbF1 = (FFD / 32) * (DIM / 64) / 4;       // 256
    const int tbF2 = (DIM / 32) * (FFD / 64) / 4;       // 256

    // ---- upfront: layer-0 weights only ----
    TxPack tp;
    tp.src[0] = qkv_w; tp.dst[0] = qkvwt; tp.K[0] = DIM; tp.N[0] = 3 * DIM;
    tp.src[1] = out_w; tp.dst[1] = outwt; tp.K[1] = DIM; tp.N[1] = DIM;
    tp.src[2] = ff_w1; tp.dst[2] = ff1t;  tp.K[2] = DIM; tp.N[2] = FFD;
    tp.src[3] = ff_w2; tp.dst[3] = ff2t;  tp.K[3] = FFD; tp.N[3] = DIM;
    tp.blk0[0] = 0;
    tp.blk0[1] = tbQ;
    tp.blk0[2] = tbQ + tbO;
    tp.blk0[3] = tbQ + tbO + tbF1;
    txd<<<tbQ + tbO + tbF1 + tbF2, 256, 0, stream>>>(tp);

    for (int l = 0; l < LAYERS; ++l) {
        bool more = (l + 1 < LAYERS);
        if (l == 0)
            ln_kernel<true, true><<<TOK, 256, 0, stream>>>(
                x, attn_g, attn_b, y, h);           // also writes h = bf16(x)
        else
            ln_kernel<true, false><<<TOK, 256, 0, stream>>>(
                h, attn_g + l * DIM, attn_b + l * DIM, y, nullptr);

        // qkv (+ next-layer qkv_w tx tail)
        {
            int gx = 3 * DIM / 128, gb = gx * (TOK / 64);
            gemm32<64, 128, 32, 64, 0><<<gb + (more ? tbQ : 0), 256, 0, stream>>>(
                y, qkvwt + l * sQ, nullptr, nullptr, qkvb,
                3 * DIM, DIM, gb, gx,
                qkv_w + (l + 1) * sQ, qkvwt + (l + 1) * sQ, DIM, 3 * DIM);
        }
        attn_kernel<<<BATCH * NH, 256, 0, stream>>>(qkvb, ob);
        // out-proj (+ next out_w tx tail)
        {
            int gx = DIM / 64, gb = gx * (TOK / 64);
            gemm32<64, 64, 32, 32, 1><<<gb + (more ? tbO : 0), 256, 0, stream>>>(
                ob, outwt + l * sO, out_b + l * DIM, h, h,
                DIM, DIM, gb, gx,
                out_w + (l + 1) * sO, outwt + (l + 1) * sO, DIM, DIM);
        }
        ln_kernel<false, false><<<TOK, 256, 0, stream>>>(
            h, ff_g + l * DIM, ff_b + l * DIM, y, nullptr);
        // ff1 (+ next ff_w1 tx tail)
        {
            int gx = FFD / 128, gb = gx * (TOK / 64);
            gemm32<64, 128, 32, 64, 2><<<gb + (more ? tbF1 : 0), 256, 0, stream>>>(
                y, ff1t + l * sF1, ff_b1 + l * FFD, nullptr, ffb,
                FFD, DIM, gb, gx,
                ff_w1 + (l + 1) * sF1, ff1t + (l + 1) * sF1, DIM, FFD);
        }
        // ff2 (+ next ff_w2 tx tail)
        {
            int gx = DIM / 64, gb = gx * (TOK / 64);
            gemm32<64, 64, 32, 32, 1><<<gb + (more ? tbF2 : 0), 256, 0, stream>>>(
                ffb, ff2t + l * sF2, ff_b2 + l * DIM, h, h,
                DIM, FFD, gb, gx,
                ff_w2 + (l + 1) * sF2, ff2t + (l + 1) * sF2, FFD, DIM);
        }
    }

    // heads: head1 reads h directly (x_comb = first 2048 bf16 of each batch block)
    gemm_hd<<<dim3(IDH / 64, 1, NHEAD_OUT), 256, 0, stream>>>(
        h, hw1, hb1, h1,
        IDH, 2 * DIM, (long)SEQ * DIM,
        0, (long)2 * DIM * IDH, IDH, (long)BATCH * IDH);
    gemm_hd<<<dim3(IDH / 64, 1, NHEAD_OUT), 256, 0, stream>>>(
        h1, hw2, hb2, h2,
        IDH, IDH, IDH,
        (long)BATCH * IDH, (long)IDH * IDH, IDH, (long)BATCH * IDH);
    head3_kernel<<<(NHEAD_OUT * BATCH * 64) / 256, 256, 0, stream>>>(h2, hw3, hb3, out);
}

// Round 19
// 515.016 us; speedup vs baseline: 1.1713x; 1.0067x over previous
//
#include <hip/hip_runtime.h>
#include <math.h>

static constexpr int BATCH = 64;
static constexpr int SEQ   = 32;
static constexpr int TOK   = BATCH * SEQ;   // 2048
static constexpr int DIM   = 1024;
static constexpr int NH    = 16;
static constexpr int HDIM  = 64;
static constexpr int FFD   = 2048;
static constexpr int LAYERS= 4;
static constexpr int NHEAD_OUT = 26;
static constexpr int IDH   = 512;

typedef __bf16 bf16_t;
typedef __bf16 bf16x4 __attribute__((ext_vector_type(4)));
typedef __bf16 bf16x8 __attribute__((ext_vector_type(8)));
typedef float  f32x4  __attribute__((ext_vector_type(4)));
typedef float  f32x16 __attribute__((ext_vector_type(16)));
typedef unsigned short us4 __attribute__((ext_vector_type(4)));
typedef unsigned short us8 __attribute__((ext_vector_type(8)));

__device__ __forceinline__ unsigned short f2bfu(float f) {
    return __builtin_bit_cast(unsigned short, (bf16_t)f);
}

__device__ __forceinline__ void gload_lds16(const void* gp, void* lp) {
    __builtin_amdgcn_global_load_lds(
        (const __attribute__((address_space(1))) unsigned int*)gp,
        (__attribute__((address_space(3))) unsigned int*)lp,
        16, 0, 0);
}

// ---------------- fragment-tiled transpose: 4 chunks of ONE matrix ----------
// chunk (ns,kt) = 4KB: [kk(4)][lane(64)][16B]; lane l: n = ns*32+(l&31),
// k = kt*64 + kk*16 + (l>>5)*8 + j.
__device__ __forceinline__ void tx_chunks4(const float* __restrict__ src,
                                           bf16_t* __restrict__ dst,
                                           int K, int N, int base4) {
    int nkb = K >> 6;
    int kk = threadIdx.x >> 6;
    int l  = threadIdx.x & 63;
    int nl = l & 31, k8 = (l >> 5) * 8;
    int base = base4 * 4;
    #pragma unroll
    for (int q = 0; q < 4; ++q) {
        int chunk = base + q;
        int ns = chunk / nkb;
        int kt = chunk - ns * nkb;
        int n = ns * 32 + nl;
        int kb = kt * 64 + kk * 16 + k8;
        us8 o;
        #pragma unroll
        for (int j = 0; j < 8; ++j)
            o[j] = f2bfu(src[(long)(kb + j) * N + n]);
        *(us8*)(dst + (long)chunk * 2048 + kk * 512 + l * 8) = o;
    }
}

// ---------------- upfront transpose (single matrix) ----------------
__global__ __launch_bounds__(256) void txd1(const float* __restrict__ src,
                                            bf16_t* __restrict__ dst,
                                            int K, int N) {
    tx_chunks4(src, dst, K, N, blockIdx.x);
}

// ---------------- block-wide sum (256 threads = 4 waves) ----------------
__device__ __forceinline__ float block_sum(float v, float* red) {
    #pragma unroll
    for (int off = 32; off > 0; off >>= 1) v += __shfl_down(v, off);
    int lane = threadIdx.x & 63;
    int w    = threadIdx.x >> 6;
    if (lane == 0) red[w] = v;
    __syncthreads();
    float t = red[0] + red[1] + red[2] + red[3];
    __syncthreads();
    return t;
}

// ---------------- LayerNorm -> bf16 output
// F32IN: input is fp32 x; also writes h = bf16(x) (layer-0 fusion of cvt).
template<bool PRE, bool F32IN>
__global__ __launch_bounds__(256) void ln_kernel(const void* __restrict__ xv,
                                                 const float* __restrict__ g,
                                                 const float* __restrict__ b,
                                                 bf16_t* __restrict__ y,
                                                 bf16_t* __restrict__ hout) {
    __shared__ float red[4];
    long row = blockIdx.x;
    int tid = threadIdx.x;
    float4 v;
    if (F32IN) {
        const float* xr = (const float*)xv + row * DIM;
        v = *(const float4*)(xr + tid * 4);
        us4 hc;
        hc.x = f2bfu(v.x); hc.y = f2bfu(v.y); hc.z = f2bfu(v.z); hc.w = f2bfu(v.w);
        *(us4*)(hout + row * DIM + tid * 4) = hc;
        v.x = (float)(bf16_t)v.x; v.y = (float)(bf16_t)v.y;
        v.z = (float)(bf16_t)v.z; v.w = (float)(bf16_t)v.w;
    } else {
        const bf16_t* xr = (const bf16_t*)xv + row * DIM;
        bf16x4 r4 = *(const bf16x4*)(xr + tid * 4);
        v.x = (float)r4[0]; v.y = (float)r4[1]; v.z = (float)r4[2]; v.w = (float)r4[3];
    }
    if (PRE) {
        float s  = block_sum(v.x + v.y + v.z + v.w, red);
        float mu = s * (1.0f / DIM);
        v.x -= mu; v.y -= mu; v.z -= mu; v.w -= mu;
        float ss = block_sum(v.x*v.x + v.y*v.y + v.z*v.z + v.w*v.w, red);
        float r  = 1.0f / sqrtf(ss * (1.0f / DIM) + 1e-6f);
        v.x *= r; v.y *= r; v.z *= r; v.w *= r;
    }
    float s  = block_sum(v.x + v.y + v.z + v.w, red);
    float mu = s * (1.0f / DIM);
    v.x -= mu; v.y -= mu; v.z -= mu; v.w -= mu;
    float ss = block_sum(v.x*v.x + v.y*v.y + v.z*v.z + v.w*v.w, red);
    float r  = 1.0f / sqrtf(ss * (1.0f / DIM) + 1e-5f);
    float4 gg = *(const float4*)(g + tid * 4);
    float4 bb = *(const float4*)(b + tid * 4);
    us4 o;
    o.x = f2bfu(v.x * r * gg.x + bb.x);
    o.y = f2bfu(v.y * r * gg.y + bb.y);
    o.z = f2bfu(v.z * r * gg.z + bb.z);
    o.w = f2bfu(v.w * r * gg.w + bb.w);
    *(us4*)(y + row * DIM + tid * 4) = o;
}

// ---------------- 32x32x16 MFMA GEMM + optional tx-tail blocks
// 1D grid: bid < gemmBlocks -> GEMM tile (bx=bid%gx, by=bid/gx);
// else -> transpose 4 chunks of the NEXT GEMM's weight (one-step chain,
// ordering guaranteed by kernel boundary before the consumer launch).
// EPI: 0 = none, 1 = +bias +resid(bf16), 2 = +bias gelu. All bf16 out.
template<int BM, int BN, int WM, int WN, int EPI>
__global__ __launch_bounds__(256) void gemm32(
    const bf16_t* __restrict__ A, const bf16_t* __restrict__ BT,
    const float* __restrict__ bias, const bf16_t* __restrict__ resid,
    bf16_t* __restrict__ Ch,
    int N, int K, int gemmBlocks, int gx,
    const float* __restrict__ txsrc, bf16_t* __restrict__ txdst,
    int txK, int txN)
{
    constexpr int WAVES_N = BN / WN;
    constexpr int FM = WM / 32, FN = WN / 32;
    constexpr int NSTG = BM / 32 + BN / 32;

    __shared__ bf16_t As[2][BM * 64];
    __shared__ bf16_t Bs[2][BN * 64];

    int bid = blockIdx.x;
    if (bid >= gemmBlocks) {
        tx_chunks4(txsrc, txdst, txK, txN, bid - gemmBlocks);
        return;
    }
    int bx = bid % gx, by = bid / gx;

    int tid  = threadIdx.x;
    int wave = tid >> 6, lane = tid & 63;
    int wr = wave / WAVES_N, wc = wave % WAVES_N;
    int m0 = by * BM, n0 = bx * BN;

    f32x16 acc[FM][FN];
    #pragma unroll
    for (int m = 0; m < FM; ++m)
        #pragma unroll
        for (int n = 0; n < FN; ++n)
            #pragma unroll
            for (int r = 0; r < 16; ++r)
                acc[m][n][r] = 0.f;

    long rsb = (long)K * 2;                  // row byte stride (A)
    int  lr  = lane & 31;
    int  lkb = (lane >> 5) * 16;
    int  nkb = K >> 6;

    const char* Abase = (const char*)A + (long)(m0 + lr) * rsb + lkb;
    const char* Bbase = (const char*)BT + (long)(n0 >> 5) * nkb * 4096 + lane * 16;

    auto stage = [&](int c, int t) {
        long kb = (long)t * 128;             // t*64 k * 2B (A side)
        #pragma unroll
        for (int i = 0; i < BM / 32; ++i) {
            int b = i * 4 + wave;
            gload_lds16(Abase + (long)(b >> 2) * 32 * rsb + (b & 3) * 32 + kb,
                        (char*)&As[c][0] + b * 1024);
        }
        #pragma unroll
        for (int i = 0; i < BN / 32; ++i) {
            int b = i * 4 + wave;            // s = b>>2, kk = b&3
            gload_lds16(Bbase + ((long)(b >> 2) * nkb + t) * 4096 + (b & 3) * 1024,
                        (char*)&Bs[c][0] + b * 1024);
        }
    };

    int nt = K >> 6;
    stage(0, 0);
    int cur = 0;
    for (int t = 0; t < nt; ++t) {
        if (t + 1 < nt) {
            stage(cur ^ 1, t + 1);
            asm volatile("s_waitcnt vmcnt(%c0)" :: "i"(NSTG) : "memory");
        } else {
            asm volatile("s_waitcnt vmcnt(0)" ::: "memory");
        }
        __builtin_amdgcn_s_barrier();
        asm volatile("" ::: "memory");
        bf16x8 af[FM][4], bq[FN][4];
        #pragma unroll
        for (int m = 0; m < FM; ++m)
            #pragma unroll
            for (int kk = 0; kk < 4; ++kk)
                af[m][kk] = *(const bf16x8*)((const char*)&As[cur][0] +
                            ((wr * FM + m) * 4 + kk) * 1024 + (lane << 4));
        #pragma unroll
        for (int n = 0; n < FN; ++n)
            #pragma unroll
            for (int kk = 0; kk < 4; ++kk)
                bq[n][kk] = *(const bf16x8*)((const char*)&Bs[cur][0] +
                            ((wc * FN + n) * 4 + kk) * 1024 + (lane << 4));
        #pragma unroll
        for (int kk = 0; kk < 4; ++kk)
            #pragma unroll
            for (int m = 0; m < FM; ++m)
                #pragma unroll
                for (int n = 0; n < FN; ++n)
                    acc[m][n] = __builtin_amdgcn_mfma_f32_32x32x16_bf16(
                        af[m][kk], bq[n][kk], acc[m][n], 0, 0, 0);
        asm volatile("" ::: "memory");
        __builtin_amdgcn_s_barrier();
        cur ^= 1;
    }

    // C/D layout: col = lane&31, row = (reg&3) + 8*(reg>>2) + 4*(lane>>5)
    int rbase = 4 * (lane >> 5);
    #pragma unroll
    for (int m = 0; m < FM; ++m) {
        #pragma unroll
        for (int n = 0; n < FN; ++n) {
            int colI = n0 + wc * WN + n * 32 + (lane & 31);
            float bb = (EPI != 0) ? bias[colI] : 0.f;
            #pragma unroll
            for (int r = 0; r < 16; ++r) {
                int rowI = m0 + wr * WM + m * 32 + rbase + (r & 3) + 8 * (r >> 2);
                float v = acc[m][n][r] + bb;
                if (EPI == 2) v = 0.5f * v * (1.0f + erff(v * 0.70710678118654752f));
                long off = (long)rowI * N + colI;
                if (EPI == 1) v += (float)resid[off];
                Ch[off] = (bf16_t)v;
            }
        }
    }
}

// ---------------- head GEMM: A bf16 [M][K] (row stride aStride), B fp32 [K][N]
__global__ __launch_bounds__(256) void gemm_hd(
    const bf16_t* __restrict__ A, const float* __restrict__ Bw,
    const float* __restrict__ bias, bf16_t* __restrict__ C,
    int N, int K, long aStride, long sA, long sB, long sbias, long sC)
{
    long g = blockIdx.z;
    A += g * sA;
    const float* Bp = Bw + g * sB;
    bias += g * sbias;
    bf16_t* Cp = C + g * sC;

    __shared__ bf16_t As[2][64 * 64];
    __shared__ float  Bf[2][64 * 64];

    int tid = threadIdx.x, wave = tid >> 6, lane = tid & 63;
    int wr = wave >> 1, wc = wave & 1;
    int n0 = blockIdx.x * 64;

    f32x4 acc[2][2];
    #pragma unroll
    for (int m = 0; m < 2; ++m)
        #pragma unroll
        for (int n = 0; n < 2; ++n)
            acc[m][n] = f32x4{0.f, 0.f, 0.f, 0.f};

    long rsb = aStride * 2;                  // A row byte stride
    int  lr  = lane & 15;
    int  lkb = (lane >> 4) * 16;
    const char* Abase = (const char*)A + (long)lr * rsb + lkb;   // m0 = 0

    auto stage = [&](int c, int t) {
        long kb = (long)t * 128;
        #pragma unroll
        for (int i = 0; i < 2; ++i) {            // A: 64x64 bf16, fragment-ordered
            int b = i * 4 + wave;
            gload_lds16(Abase + (long)(b >> 1) * 16 * rsb + (b & 1) * 64 + kb,
                        (char*)&As[c][0] + b * 1024);
        }
        #pragma unroll
        for (int i = 0; i < 4; ++i) {            // B: 64k x 64n fp32 row-major
            int ch = i * 4 + wave;
            int row = ch * 4 + (lane >> 4);
            gload_lds16((const char*)Bp + ((long)(t * 64 + row) * N + n0) * 4 + (lane & 15) * 16,
                        (char*)&Bf[c][0] + ch * 1024);
        }
    };

    int nt = K >> 6;
    stage(0, 0);
    int cur = 0;
    for (int t = 0; t < nt; ++t) {
        if (t + 1 < nt) {
            stage(cur ^ 1, t + 1);
            asm volatile("s_waitcnt vmcnt(6)" ::: "memory");
        } else {
            asm volatile("s_waitcnt vmcnt(0)" ::: "memory");
        }
        __builtin_amdgcn_s_barrier();
        asm volatile("" ::: "memory");
        bf16x8 af[2][2], bq[2][2];
        #pragma unroll
        for (int m = 0; m < 2; ++m)
            #pragma unroll
            for (int h = 0; h < 2; ++h)
                af[m][h] = *(const bf16x8*)((const char*)&As[cur][0] +
                           ((wr * 2 + m) * 2 + h) * 1024 + (lane << 4));
        #pragma unroll
        for (int n = 0; n < 2; ++n) {
            int nl = wc * 32 + n * 16 + lr;
            #pragma unroll
            for (int h = 0; h < 2; ++h) {
                #pragma unroll
                for (int j = 0; j < 8; ++j) {
                    float v = Bf[cur][(h * 32 + (lane >> 4) * 8 + j) * 64 + nl];
                    bq[n][h][j] = (bf16_t)v;
                }
            }
        }
        #pragma unroll
        for (int h = 0; h < 2; ++h)
            #pragma unroll
            for (int m = 0; m < 2; ++m)
                #pragma unroll
                for (int n = 0; n < 2; ++n)
                    acc[m][n] = __builtin_amdgcn_mfma_f32_16x16x32_bf16(
                        af[m][h], bq[n][h], acc[m][n], 0, 0, 0);
        asm volatile("" ::: "memory");
        __builtin_amdgcn_s_barrier();
        cur ^= 1;
    }

    int lq = (lane >> 4) * 4;
    #pragma unroll
    for (int m = 0; m < 2; ++m) {
        #pragma unroll
        for (int n = 0; n < 2; ++n) {
            int colI = n0 + wc * 32 + n * 16 + lr;
            float bb = bias[colI];
            #pragma unroll
            for (int j = 0; j < 4; ++j) {
                int rowI = wr * 32 + m * 16 + lq + j;
                float v = fmaxf(acc[m][n][j] + bb, 0.0f);
                Cp[(long)rowI * N + colI] = (bf16_t)v;
            }
        }
    }
}

// ---------------- fused attention: one block per (batch, head). T=32, HD=64.
__global__ __launch_bounds__(256) void attn_kernel(const bf16_t* __restrict__ qkv,
                                                   bf16_t* __restrict__ o) {
    int bh = blockIdx.x;
    int b  = bh >> 4;
    int hh = bh & 15;
    __shared__ float qs[32][65];
    __shared__ float kt[64][36];
    __shared__ float vs[32][68];
    __shared__ float ps[32][33];
    const bf16_t* base = qkv + (long)b * SEQ * (3 * DIM) + hh * HDIM;
    int tid = threadIdx.x;

    {
        int t = tid >> 3, c = (tid & 7) * 8;
        bf16x8 qv = *(const bf16x8*)(base + (long)t * 3 * DIM + c);
        bf16x8 kv = *(const bf16x8*)(base + (long)t * 3 * DIM + DIM + c);
        bf16x8 vv = *(const bf16x8*)(base + (long)t * 3 * DIM + 2 * DIM + c);
        #pragma unroll
        for (int j = 0; j < 8; ++j) {
            int d = c + j;
            qs[t][d] = (float)qv[j];
            kt[d][(((t >> 2) ^ ((d >> 2) & 7)) << 2) + (t & 3)] = (float)kv[j];
            vs[t][d] = (float)vv[j];
        }
    }
    __syncthreads();

    {
        int r  = tid >> 3;
        int c0 = (tid & 7) * 4;
        f32x4 acc = {0.f, 0.f, 0.f, 0.f};
        #pragma unroll
        for (int d = 0; d < 64; ++d) {
            float qv = qs[r][d];
            float4 kv = *(const float4*)&kt[d][(((c0 >> 2) ^ ((d >> 2) & 7)) << 2)];
            acc[0] = fmaf(qv, kv.x, acc[0]);
            acc[1] = fmaf(qv, kv.y, acc[1]);
            acc[2] = fmaf(qv, kv.z, acc[2]);
            acc[3] = fmaf(qv, kv.w, acc[3]);
        }
        #pragma unroll
        for (int i = 0; i < 4; ++i) ps[r][c0 + i] = acc[i] * 0.125f;
    }
    __syncthreads();

    if (tid < 32) {
        float mx = -1e30f;
        for (int c = 0; c < 32; ++c) mx = fmaxf(mx, ps[tid][c]);
        float sum = 0.f;
        for (int c = 0; c < 32; ++c) { float e = expf(ps[tid][c] - mx); ps[tid][c] = e; sum += e; }
        float inv = 1.f / sum;
        for (int c = 0; c < 32; ++c) ps[tid][c] *= inv;
    }
    __syncthreads();

    {
        int r  = tid >> 3;
        int d0 = (tid & 7) * 8;
        float acc[8] = {};
        #pragma unroll
        for (int c = 0; c < 32; ++c) {
            float pv = ps[r][c];
            float4 v0 = *(const float4*)&vs[c][d0];
            float4 v1 = *(const float4*)&vs[c][d0 + 4];
            acc[0] = fmaf(pv, v0.x, acc[0]);
            acc[1] = fmaf(pv, v0.y, acc[1]);
            acc[2] = fmaf(pv, v0.z, acc[2]);
            acc[3] = fmaf(pv, v0.w, acc[3]);
            acc[4] = fmaf(pv, v1.x, acc[4]);
            acc[5] = fmaf(pv, v1.y, acc[5]);
            acc[6] = fmaf(pv, v1.z, acc[6]);
            acc[7] = fmaf(pv, v1.w, acc[7]);
        }
        us8 ov;
        #pragma unroll
        for (int j = 0; j < 8; ++j) ov[j] = f2bfu(acc[j]);
        *(us8*)(o + (long)b * SEQ * DIM + (long)r * DIM + hh * HDIM + d0) = ov;
    }
}

// ---------------- head layer 3: one wave per (n, b), dot-512
__global__ __launch_bounds__(256) void head3_kernel(const bf16_t* __restrict__ h2,
                                                    const float* __restrict__ w3,
                                                    const float* __restrict__ b3,
                                                    float* __restrict__ out) {
    int gid  = blockIdx.x * 256 + threadIdx.x;
    int wave = gid >> 6;
    int lane = gid & 63;
    if (wave >= NHEAD_OUT * BATCH) return;
    int n = wave >> 6;
    int b = wave & 63;
    const bf16_t* a = h2 + ((long)n * BATCH + b) * IDH;
    const float*  w = w3 + (long)n * IDH;
    float acc = 0.f;
    #pragma unroll
    for (int i = lane; i < IDH; i += 64) acc = fmaf((float)a[i], w[i], acc);
    #pragma unroll
    for (int off = 32; off > 0; off >>= 1) acc += __shfl_down(acc, off);
    if (lane == 0) out[b * NHEAD_OUT + n] = acc + b3[n];
}

extern "C" void kernel_launch(void* const* d_in, const int* in_sizes, int n_in,
                              void* d_out, int out_size, void* d_ws, size_t ws_size,
                              hipStream_t stream) {
    const float* x      = (const float*)d_in[0];
    const float* qkv_w  = (const float*)d_in[1];
    const float* out_w  = (const float*)d_in[2];
    const float* out_b  = (const float*)d_in[3];
    const float* attn_g = (const float*)d_in[4];
    const float* attn_b = (const float*)d_in[5];
    const float* ff_g   = (const float*)d_in[6];
    const float* ff_b   = (const float*)d_in[7];
    const float* ff_w1  = (const float*)d_in[8];
    const float* ff_b1  = (const float*)d_in[9];
    const float* ff_w2  = (const float*)d_in[10];
    const float* ff_b2  = (const float*)d_in[11];
    const float* hw1    = (const float*)d_in[12];
    const float* hb1    = (const float*)d_in[13];
    const float* hw2    = (const float*)d_in[14];
    const float* hb2    = (const float*)d_in[15];
    const float* hw3    = (const float*)d_in[16];
    const float* hb3    = (const float*)d_in[17];
    float* out = (float*)d_out;

    char* p = (char*)d_ws;
    bf16_t* h     = (bf16_t*)p;           p += (long)TOK * DIM * 2;
    bf16_t* qkvb  = (bf16_t*)p;           p += (long)TOK * 3 * DIM * 2;
    bf16_t* y     = (bf16_t*)p;           p += (long)TOK * DIM * 2;
    bf16_t* ob    = (bf16_t*)p;           p += (long)TOK * DIM * 2;
    bf16_t* ffb   = (bf16_t*)p;           p += (long)TOK * FFD * 2;
    bf16_t* h1    = (bf16_t*)p;           p += (long)NHEAD_OUT * BATCH * IDH * 2;
    bf16_t* h2    = (bf16_t*)p;           p += (long)NHEAD_OUT * BATCH * IDH * 2;
    bf16_t* qkvwt = (bf16_t*)p;           p += (long)LAYERS * DIM * 3 * DIM * 2;
    bf16_t* outwt = (bf16_t*)p;           p += (long)LAYERS * DIM * DIM * 2;
    bf16_t* ff1t  = (bf16_t*)p;           p += (long)LAYERS * DIM * FFD * 2;
    bf16_t* ff2t  = (bf16_t*)p;           p += (long)LAYERS * FFD * DIM * 2;

    // per-layer weight strides (elements)
    const long sQ = (long)DIM * 3 * DIM;
    const long sO = (long)DIM * DIM;
    const long sF1 = (long)DIM * FFD;
    const long sF2 = (long)FFD * DIM;
    // tx tail blocks per matrix (4 chunks/block)
    const int tbQ  = (3 * DIM / 32) * (DIM / 64) / 4;   // 384
    const int tbO  = (DIM / 32) * (DIM / 64) / 4;       // 128
    const int tbF1 = (FFD / 32) * (DIM / 64) / 4;       // 256
    const int tbF2 = (DIM / 32) * (FFD / 64) / 4;       // 256

    // ---- upfront: layer-0 qkv weight only (one-step tx chain) ----
    txd1<<<tbQ, 256, 0, stream>>>(qkv_w, qkvwt, DIM, 3 * DIM);

    for (int l = 0; l < LAYERS; ++l) {
        bool more = (l + 1 < LAYERS);
        if (l == 0)
            ln_kernel<true, true><<<TOK, 256, 0, stream>>>(
                x, attn_g, attn_b, y, h);           // also writes h = bf16(x)
        else
            ln_kernel<true, false><<<TOK, 256, 0, stream>>>(
                h, attn_g + l * DIM, attn_b + l * DIM, y, nullptr);

        // qkv  (+ tx tail: THIS layer's out_w)
        {
            int gx = 3 * DIM / 128, gb = gx * (TOK / 64);
            gemm32<64, 128, 32, 64, 0><<<gb + tbO, 256, 0, stream>>>(
                y, qkvwt + l * sQ, nullptr, nullptr, qkvb,
                3 * DIM, DIM, gb, gx,
                out_w + l * sO, outwt + l * sO, DIM, DIM);
        }
        attn_kernel<<<BATCH * NH, 256, 0, stream>>>(qkvb, ob);
        // out-proj  (+ tx tail: THIS layer's ff_w1)
        {
            int gx = DIM / 64, gb = gx * (TOK / 64);
            gemm32<64, 64, 32, 32, 1><<<gb + tbF1, 256, 0, stream>>>(
                ob, outwt + l * sO, out_b + l * DIM, h, h,
                DIM, DIM, gb, gx,
                ff_w1 + l * sF1, ff1t + l * sF1, DIM, FFD);
        }
        ln_kernel<false, false><<<TOK, 256, 0, stream>>>(
            h, ff_g + l * DIM, ff_b + l * DIM, y, nullptr);
        // ff1  (+ tx tail: THIS layer's ff_w2)
        {
            int gx = FFD / 128, gb = gx * (TOK / 64);
            gemm32<64, 128, 32, 64, 2><<<gb + tbF2, 256, 0, stream>>>(
                y, ff1t + l * sF1, ff_b1 + l * FFD, nullptr, ffb,
                FFD, DIM, gb, gx,
                ff_w2 + l * sF2, ff2t + l * sF2, FFD, DIM);
        }
        // ff2  (+ tx tail: NEXT layer's qkv_w, if any)
        {
            int gx = DIM / 64, gb = gx * (TOK / 64);
            gemm32<64, 64, 32, 32, 1><<<gb + (more ? tbQ : 0), 256, 0, stream>>>(
                ffb, ff2t + l * sF2, ff_b2 + l * DIM, h, h,
                DIM, FFD, gb, gx,
                qkv_w + (l + 1) * sQ, qkvwt + (l + 1) * sQ, DIM, 3 * DIM);
        }
    }

    // heads: head1 reads h directly (x_comb = first 2048 bf16 of each batch block)
    gemm_hd<<<dim3(IDH / 64, 1, NHEAD_OUT), 256, 0, stream>>>(
        h, hw1, hb1, h1,
        IDH, 2 * DIM, (long)SEQ * DIM,
        0, (long)2 * DIM * IDH, IDH, (long)BATCH * IDH);
    gemm_hd<<<dim3(IDH / 64, 1, NHEAD_OUT), 256, 0, stream>>>(
        h1, hw2, hb2, h2,
        IDH, IDH, IDH,
        (long)BATCH * IDH, (long)IDH * IDH, IDH, (long)BATCH * IDH);
    head3_kernel<<<(NHEAD_OUT * BATCH * 64) / 256, 256, 0, stream>>>(h2, hw3, hb3, out);
}